// Round 6
// baseline (239.157 us; speedup 1.0000x reference)
//
#include <hip/hip_runtime.h>
#include <math.h>

#define BLOCK 256
#define CPT 4                 // edges per thread
#define TILE (BLOCK * CPT)    // 1024 edges per block; 3.2M = 3125 * 1024 exactly
#define EPS 1e-6f

// R6 = R5 resubmitted verbatim (R5 bench died in container acquisition — same
// infra failure mode as R2, which ran fine on resubmission. No compile error,
// no verdict, no counters. Kernel re-audited: OOB/hang/alignment/graph-capture
// all clean.)
//
// R5 design notes (theory-first):
// - R4 post-mortem: spills fixed (WRITE back to exactly 75000KB), occupancy
//   65%, yet dur 94.2us > R1's 86.5 -> occupancy is NOT the binding resource.
//   Wave-lifetime arithmetic: ~17K cycles lifetime per ~1K cycles of issue --
//   waves are ~90% stalled on the serial edge->gather->vmcnt(0)->compute chain.
//   Kernel is intra-wave-serialization-bound.
// - R5: software-pipeline in registers. 4 edges/thread (two ping-pong register
//   sets): issue j+1's node gathers + pose loads, then compute j. Compiler
//   emits counted vmcnt(N) for register deps -> prefetch stays in flight under
//   ~1Kcy of compute >> gather latency. No LDS for inputs at all; LDS only for
//   the 6KB out-staging (16B-aligned coalesced stores, proven WRITE=75000).
// - Per-lane node loads are ALIGNED 2x dwordx4 from 32B records (R4's +37MB
//   overfetch came from stride-28 STRADDLING pose loads; aligned node loads
//   don't straddle). Pose straddle may still overfetch but we're at 31% BW --
//   latency is hidden by the pipeline, bandwidth has headroom.
// - Keep: repack_nodes prologue, single-divide sincos-free log map (|qE|=1),
//   no __launch_bounds__ min-waves (R3 spill lesson), zero __syncthreads.
// Predicted: dur 94->55-75us, VALUBusy 28->45-65 (signature of stalls gone),
// WRITE exactly 75000, bank-conflict <0.5M, VGPR 80-110 (spill alarm: WRITE>75000).

struct F3 { float x, y, z; };
struct F4 { float x, y, z, w; };

__device__ __forceinline__ F3 cross3(F3 a, F3 b) {
    return F3{a.y * b.z - a.z * b.y,
              a.z * b.x - a.x * b.z,
              a.x * b.y - a.y * b.x};
}
__device__ __forceinline__ F3 add3(F3 a, F3 b) { return F3{a.x + b.x, a.y + b.y, a.z + b.z}; }
__device__ __forceinline__ F3 neg3(F3 a) { return F3{-a.x, -a.y, -a.z}; }

__device__ __forceinline__ F3 qrot(F4 q, F3 v) {
    F3 u{q.x, q.y, q.z};
    F3 t = cross3(u, v);
    t.x *= 2.0f; t.y *= 2.0f; t.z *= 2.0f;
    F3 c = cross3(u, t);
    return F3{v.x + q.w * t.x + c.x,
              v.y + q.w * t.y + c.y,
              v.z + q.w * t.z + c.z};
}
__device__ __forceinline__ F4 qmul(F4 q, F4 r) {
    return F4{
        q.w * r.x + q.x * r.w + q.y * r.z - q.z * r.y,
        q.w * r.y - q.x * r.z + q.y * r.w + q.z * r.x,
        q.w * r.z + q.x * r.y - q.y * r.x + q.z * r.w,
        q.w * r.w - q.x * r.x - q.y * r.y - q.z * r.z};
}

// Full edge-error + se3_log, sincos-free, single-divide (|qE| = 1 identities).
__device__ __forceinline__ void se3_error_log(
    F3 tp, F4 qp, F3 t1, F4 q1, F3 t2, F4 q2, float o[6])
{
    F4 qpc{-qp.x, -qp.y, -qp.z, qp.w};
    F3 tpi = neg3(qrot(qpc, tp));

    F3 tA = add3(tpi, qrot(qpc, t2));
    F4 qA = qmul(qpc, q2);

    F4 q1c{-q1.x, -q1.y, -q1.z, q1.w};
    F3 t1i = neg3(qrot(q1c, t1));

    F3 tE = add3(tA, qrot(qA, t1i));
    F4 qE = qmul(qA, q1c);

    F3 v{qE.x, qE.y, qE.z};
    float w = qE.w;
    float nn = sqrtf(v.x * v.x + v.y * v.y + v.z * v.z);

    float scale, c;
    if (nn > EPS) {
        float ang = 2.0f * atan2f(nn, w);   // == theta == |phi|
        // one divide: u = 1/(ang*nn); 1/ang = u*nn; 1/nn = u*ang
        float u = 1.0f / (ang * nn);
        scale = u * ang * ang;              // = ang/nn
        // (1+cos)/(2*theta*sin) with cos=w^2-nn^2, sin=2*nn*w (unit qE)
        //   = 1/ang^2 - w/(2*nn*ang) = u*(u*nn*nn - 0.5*w)
        c = u * (u * nn * nn - 0.5f * w);
    } else {
        // theta ~ 2*nn <= 2e-6: c-term multiplies O(theta^2) -> 1/12 exact limit
        scale = 2.0f / ((fabsf(w) > EPS) ? w : 1.0f);
        c = 1.0f / 12.0f;
    }

    F3 phi{v.x * scale, v.y * scale, v.z * scale};
    F3 pxt = cross3(phi, tE);
    F3 ppxt = cross3(phi, pxt);
    o[0] = tE.x - 0.5f * pxt.x + c * ppxt.x;
    o[1] = tE.y - 0.5f * pxt.y + c * ppxt.y;
    o[2] = tE.z - 0.5f * pxt.z + c * ppxt.z;
    o[3] = phi.x; o[4] = phi.y; o[5] = phi.z;
}

// ---- prologue: nodes [N,7] -> d_ws [N,8] (32B records, 16B-aligned) ----
__global__ void __launch_bounds__(BLOCK) repack_nodes_kernel(
    const float* __restrict__ nodes, float* __restrict__ nodes8, int total7)
{
    int idx = blockIdx.x * BLOCK + threadIdx.x;
    int stride = gridDim.x * BLOCK;
    for (; idx < total7; idx += stride) {
        int node = idx / 7;
        int comp = idx - node * 7;
        nodes8[node * 8 + comp] = nodes[idx];
    }
}

__device__ __forceinline__ void load_nodes(
    const float* __restrict__ nodes8, int2 ed,
    float4& a1, float4& b1, float4& a2, float4& b2)
{
    const float4* n1p = (const float4*)(nodes8 + (size_t)ed.x * 8);
    const float4* n2p = (const float4*)(nodes8 + (size_t)ed.y * 8);
    a1 = n1p[0]; b1 = n1p[1];
    a2 = n2p[0]; b2 = n2p[1];
}

__device__ __forceinline__ void load_pose(
    const float* __restrict__ poses, long long e, float pa[4], float pb[4])
{
    const char* pp = (const char*)poses + (size_t)e * 28;
    __builtin_memcpy(pa, pp, 16);        // t.xyz, q.x
    __builtin_memcpy(pb, pp + 12, 16);   // q.xyzw
}

__device__ __forceinline__ void compute_store(
    const float pa[4], const float pb[4],
    float4 a1, float4 b1, float4 a2, float4 b2,
    float* __restrict__ so,       // &SO[w][0] as float*
    const float4* __restrict__ SOw,
    float4* __restrict__ odst_j,  // out tile slice for this j
    int l)
{
    F3 tp{pa[0], pa[1], pa[2]};
    F4 qp{pb[0], pb[1], pb[2], pb[3]};
    F3 t1{a1.x, a1.y, a1.z};
    F4 q1{a1.w, b1.x, b1.y, b1.z};
    F3 t2{a2.x, a2.y, a2.z};
    F4 q2{a2.w, b2.x, b2.y, b2.z};

    float o6[6];
    se3_error_log(tp, qp, t1, q1, t2, q2, o6);

    // wave-private out staging (LDS ops from one wave are processed in order;
    // safe to reuse the buffer across j with no extra sync)
    so[l * 6 + 0] = o6[0];
    so[l * 6 + 1] = o6[1];
    so[l * 6 + 2] = o6[2];
    so[l * 6 + 3] = o6[3];
    so[l * 6 + 4] = o6[4];
    so[l * 6 + 5] = o6[5];
    asm volatile("s_waitcnt lgkmcnt(0)" ::: "memory");  // own wave's ds_writes drained

    odst_j[l] = SOw[l];
    if (l < 32) odst_j[64 + l] = SOw[64 + l];
}

__global__ void __launch_bounds__(BLOCK) pose_graph_kernel(
    const int* __restrict__ edges,     // [n,2] int32
    const float* __restrict__ poses,   // [n,7]
    const float* __restrict__ nodes8,  // [N_NODES,8] repacked
    float* __restrict__ out,           // [n,6]
    int n)
{
    __shared__ float4 SO[4][96];   // per-wave out staging: 6144 B total

    const int tid = threadIdx.x;
    const int l = tid & 63;
    const int w = tid >> 6;
    const long long base = (long long)blockIdx.x * TILE;

    if (base + TILE <= (long long)n) {
        const long long e0 = base + tid;

        // ---- all 4 edge-index loads upfront (coalesced int2, one wait) ----
        int2 ed0 = ((const int2*)edges)[e0];
        int2 ed1 = ((const int2*)edges)[e0 + BLOCK];
        int2 ed2 = ((const int2*)edges)[e0 + 2 * BLOCK];
        int2 ed3 = ((const int2*)edges)[e0 + 3 * BLOCK];

        float* so = (float*)&SO[w][0];
        const float4* SOw = &SO[w][0];
        float4* odst = (float4*)(out + base * 6);   // base*24B, 16B-aligned
        // wave w's slice for iteration j: odst + j*384 + w*96

        // ---- two ping-pong register sets; depth-1 pipeline, no copies ----
        float4 Aa, Ab, Ac, Ad; float Apa[4], Apb[4];   // set A
        float4 Ba, Bb, Bc, Bd; float Bpa[4], Bpb[4];   // set B

        // prologue: j=0 into A, j=1 into B
        load_nodes(nodes8, ed0, Aa, Ab, Ac, Ad);
        load_pose(poses, e0, Apa, Apb);
        load_nodes(nodes8, ed1, Ba, Bb, Bc, Bd);
        load_pose(poses, e0 + BLOCK, Bpa, Bpb);

        // j=0: compute A (waits only A's loads; B's stay in flight)
        compute_store(Apa, Apb, Aa, Ab, Ac, Ad, so, SOw, odst + 0 * 384 + w * 96, l);
        // prefetch j=2 into A
        load_nodes(nodes8, ed2, Aa, Ab, Ac, Ad);
        load_pose(poses, e0 + 2 * BLOCK, Apa, Apb);

        // j=1: compute B
        compute_store(Bpa, Bpb, Ba, Bb, Bc, Bd, so, SOw, odst + 1 * 384 + w * 96, l);
        // prefetch j=3 into B
        load_nodes(nodes8, ed3, Ba, Bb, Bc, Bd);
        load_pose(poses, e0 + 3 * BLOCK, Bpa, Bpb);

        // j=2: compute A
        compute_store(Apa, Apb, Aa, Ab, Ac, Ad, so, SOw, odst + 2 * 384 + w * 96, l);
        // j=3: compute B
        compute_store(Bpa, Bpb, Ba, Bb, Bc, Bd, so, SOw, odst + 3 * 384 + w * 96, l);
    } else {
        // ---- tail tile (absent at n=3.2M): per-edge scalar path ----
        for (int j = 0; j < CPT; ++j) {
            const long long e = base + j * BLOCK + tid;
            if (e < (long long)n) {
                const int2 ed = ((const int2*)edges)[e];
                float pa[4], pb[4];
                load_pose(poses, e, pa, pb);
                float4 a1, b1, a2, b2;
                load_nodes(nodes8, ed, a1, b1, a2, b2);
                F3 tp{pa[0], pa[1], pa[2]};
                F4 qp{pb[0], pb[1], pb[2], pb[3]};
                F3 t1{a1.x, a1.y, a1.z};
                F4 q1{a1.w, b1.x, b1.y, b1.z};
                F3 t2{a2.x, a2.y, a2.z};
                F4 q2{a2.w, b2.x, b2.y, b2.z};
                float o6[6];
                se3_error_log(tp, qp, t1, q1, t2, q2, o6);
                float* op = out + e * 6;
                op[0] = o6[0]; op[1] = o6[1]; op[2] = o6[2];
                op[3] = o6[3]; op[4] = o6[4]; op[5] = o6[5];
            }
        }
    }
}

// fallback (ws too small): direct scalar gathers from [N,7] nodes
__global__ void __launch_bounds__(BLOCK) pose_graph_kernel_fallback(
    const int* __restrict__ edges, const float* __restrict__ poses,
    const float* __restrict__ nodes, float* __restrict__ out, int n)
{
    const int tid = threadIdx.x;
    const long long base = (long long)blockIdx.x * BLOCK;
    const int limit = (int)min((long long)BLOCK, (long long)n - base);
    if (tid < limit) {
        const long long e = base + tid;
        const int2 ed = ((const int2*)edges)[e];
        const float* pp = poses + e * 7;
        F3 tp{pp[0], pp[1], pp[2]};
        F4 qp{pp[3], pp[4], pp[5], pp[6]};
        const float* n1p = nodes + (size_t)ed.x * 7;
        const float* n2p = nodes + (size_t)ed.y * 7;
        F3 t1{n1p[0], n1p[1], n1p[2]};
        F4 q1{n1p[3], n1p[4], n1p[5], n1p[6]};
        F3 t2{n2p[0], n2p[1], n2p[2]};
        F4 q2{n2p[3], n2p[4], n2p[5], n2p[6]};
        float o6[6];
        se3_error_log(tp, qp, t1, q1, t2, q2, o6);
        float* op = out + e * 6;
        op[0] = o6[0]; op[1] = o6[1]; op[2] = o6[2];
        op[3] = o6[3]; op[4] = o6[4]; op[5] = o6[5];
    }
}

extern "C" void kernel_launch(void* const* d_in, const int* in_sizes, int n_in,
                              void* d_out, int out_size, void* d_ws, size_t ws_size,
                              hipStream_t stream) {
    const int* edges = (const int*)d_in[0];
    const float* poses = (const float*)d_in[1];
    const float* nodes = (const float*)d_in[2];
    float* out = (float*)d_out;

    const int n_edges = in_sizes[0] / 2;
    const int n_nodes = in_sizes[2] / 7;

    const size_t ws_needed = (size_t)n_nodes * 8 * sizeof(float);
    if (ws_size >= ws_needed) {
        float* nodes8 = (float*)d_ws;
        const int total7 = n_nodes * 7;
        const int rgrid = (total7 + BLOCK - 1) / BLOCK;
        const int grid = (n_edges + TILE - 1) / TILE;
        repack_nodes_kernel<<<rgrid, BLOCK, 0, stream>>>(nodes, nodes8, total7);
        pose_graph_kernel<<<grid, BLOCK, 0, stream>>>(edges, poses, nodes8, out, n_edges);
    } else {
        const int grid = (n_edges + BLOCK - 1) / BLOCK;
        pose_graph_kernel_fallback<<<grid, BLOCK, 0, stream>>>(edges, poses, nodes, out, n_edges);
    }
}

// Round 7
// 218.651 us; speedup vs baseline: 1.0938x; 1.0938x over previous
//
#include <hip/hip_runtime.h>
#include <math.h>

#define BLOCK 256
#define CPT 4                 // edges per thread
#define TILE (BLOCK * CPT)    // 1024 edges/block; 3.2M = 3125 * 1024 exactly
#define EPS 1e-6f

// R7 design notes (theory-first):
// - R6 post-mortem: pipelining WORKED (request rate 116 -> 150 req/us, no
//   spills) but per-lane node loads doubled gather requests (256 vs 128 per
//   wave-iter) -> net LOSS (115.7us vs R4 94.2). Model: dur = requests/rate.
// - R7 combines the two proven levers: cooperative paired gather via
//   global_load_lds (1 sector-req per random 32B record, proven R1/R4) +
//   depth-1 pipeline with COUNTED vmcnt (proven R6): double-buffered
//   wave-private LDS landing zones; iteration j+1's 4 gathers + 2 pose loads
//   stay in flight across iteration j's compute.
// - vmcnt accounting: newer-than-gathers(j) ops at the wait = poses(j)2 +
//   stores(j-1)2 + gathers(j+1)4 + poses(j+1)2 >= 8 -> vmcnt(8) always drains
//   gathers(j), keeps j+1's prefetch in flight. Last iter: vmcnt(0).
//   Memory-clobber asm + sched_barrier(0) pin ordering (rule #18).
// - LDS 32KB (4 waves x 2 x 4KB) -> 5 blocks/CU. R4 proved occupancy isn't
//   the wall; overlap is. Out-staging reuses the CURRENT buffer (free after
//   its 4 ds_read_b128 complete; next gather targets the OTHER buffer).
// Predicted: dispatch 68-78us; WRITE exactly 75000 (spill alarm); FETCH
// ~150-160MB; VGPR 70-100; LDS 32768. 94us => occupancy cost canceled
// pipelining; 115us => request model wrong.

struct F3 { float x, y, z; };
struct F4 { float x, y, z, w; };

__device__ __forceinline__ F3 cross3(F3 a, F3 b) {
    return F3{a.y * b.z - a.z * b.y,
              a.z * b.x - a.x * b.z,
              a.x * b.y - a.y * b.x};
}
__device__ __forceinline__ F3 add3(F3 a, F3 b) { return F3{a.x + b.x, a.y + b.y, a.z + b.z}; }
__device__ __forceinline__ F3 neg3(F3 a) { return F3{-a.x, -a.y, -a.z}; }

__device__ __forceinline__ F3 qrot(F4 q, F3 v) {
    F3 u{q.x, q.y, q.z};
    F3 t = cross3(u, v);
    t.x *= 2.0f; t.y *= 2.0f; t.z *= 2.0f;
    F3 c = cross3(u, t);
    return F3{v.x + q.w * t.x + c.x,
              v.y + q.w * t.y + c.y,
              v.z + q.w * t.z + c.z};
}
__device__ __forceinline__ F4 qmul(F4 q, F4 r) {
    return F4{
        q.w * r.x + q.x * r.w + q.y * r.z - q.z * r.y,
        q.w * r.y - q.x * r.z + q.y * r.w + q.z * r.x,
        q.w * r.z + q.x * r.y - q.y * r.x + q.z * r.w,
        q.w * r.w - q.x * r.x - q.y * r.y - q.z * r.z};
}

// Full edge-error + se3_log, sincos-free, single-divide (|qE| = 1 identities).
__device__ __forceinline__ void se3_error_log(
    F3 tp, F4 qp, F3 t1, F4 q1, F3 t2, F4 q2, float o[6])
{
    F4 qpc{-qp.x, -qp.y, -qp.z, qp.w};
    F3 tpi = neg3(qrot(qpc, tp));

    F3 tA = add3(tpi, qrot(qpc, t2));
    F4 qA = qmul(qpc, q2);

    F4 q1c{-q1.x, -q1.y, -q1.z, q1.w};
    F3 t1i = neg3(qrot(q1c, t1));

    F3 tE = add3(tA, qrot(qA, t1i));
    F4 qE = qmul(qA, q1c);

    F3 v{qE.x, qE.y, qE.z};
    float w = qE.w;
    float nn = sqrtf(v.x * v.x + v.y * v.y + v.z * v.z);

    float scale, c;
    if (nn > EPS) {
        float ang = 2.0f * atan2f(nn, w);   // == theta == |phi|
        float u = 1.0f / (ang * nn);
        scale = u * ang * ang;              // = ang/nn
        // (1+cos)/(2*theta*sin) with cos=w^2-nn^2, sin=2*nn*w (unit qE)
        c = u * (u * nn * nn - 0.5f * w);
    } else {
        scale = 2.0f / ((fabsf(w) > EPS) ? w : 1.0f);
        c = 1.0f / 12.0f;
    }

    F3 phi{v.x * scale, v.y * scale, v.z * scale};
    F3 pxt = cross3(phi, tE);
    F3 ppxt = cross3(phi, pxt);
    o[0] = tE.x - 0.5f * pxt.x + c * ppxt.x;
    o[1] = tE.y - 0.5f * pxt.y + c * ppxt.y;
    o[2] = tE.z - 0.5f * pxt.z + c * ppxt.z;
    o[3] = phi.x; o[4] = phi.y; o[5] = phi.z;
}

__device__ __forceinline__ void gload_lds16(const void* g, void* lds) {
    __builtin_amdgcn_global_load_lds(
        (const __attribute__((address_space(1))) void*)g,
        (__attribute__((address_space(3))) void*)lds,
        16, 0, 0);
}

// cooperative paired gather (verified R1/R3/R4): halves of one 32B record are
// fetched by ADJACENT LANES of the SAME instruction -> 1 sector request each.
__device__ __forceinline__ void gather_wave(
    const float* __restrict__ nodes8, int2 ed, int l, float4* __restrict__ GW)
{
#pragma unroll
    for (int k = 0; k < 4; ++k) {
        const int o = k * 16 + (l >> 2);
        const int m = (l & 3) ^ ((o >> 1) & 3);
        const int nx = __shfl(ed.x, o, 64);
        const int ny = __shfl(ed.y, o, 64);
        const int idx = (m & 2) ? ny : nx;
        gload_lds16((const char*)nodes8 + ((size_t)idx * 32 + (size_t)(m & 1) * 16),
                    GW + k * 64);
    }
}

__device__ __forceinline__ void load_pose(
    const float* __restrict__ poses, long long e, float pa[4], float pb[4])
{
    const char* pp = (const char*)poses + (size_t)e * 28;
    __builtin_memcpy(pa, pp, 16);        // t.xyz, q.x
    __builtin_memcpy(pb, pp + 12, 16);   // q.xyzw
}

__device__ __forceinline__ void compute_store(
    const float pa[4], const float pb[4],
    float4* __restrict__ GW,            // this iteration's (drained) buffer
    float4* __restrict__ odst_j,        // out slice for this wave+iteration
    int l)
{
    // swizzled readback (bank-balanced b128, verified R1/R3/R4)
    const int xo = (l >> 1) & 3;
    const int b4 = l * 4;
    float4 a1 = GW[b4 + (0 ^ xo)];   // node1 half0: t.xyz, q.x
    float4 b1 = GW[b4 + (1 ^ xo)];   // node1 half1: q.yzw, pad
    float4 a2 = GW[b4 + (2 ^ xo)];   // node2 half0
    float4 b2 = GW[b4 + (3 ^ xo)];   // node2 half1

    F3 tp{pa[0], pa[1], pa[2]};
    F4 qp{pb[0], pb[1], pb[2], pb[3]};
    F3 t1{a1.x, a1.y, a1.z};
    F4 q1{a1.w, b1.x, b1.y, b1.z};
    F3 t2{a2.x, a2.y, a2.z};
    F4 q2{a2.w, b2.x, b2.y, b2.z};

    float o6[6];
    se3_error_log(tp, qp, t1, q1, t2, q2, o6);

    // out staging reuses THIS buffer (its ds_reads above completed before any
    // math used them; next gather targets the other buffer)
    float* Gf = (float*)GW;
    Gf[l * 6 + 0] = o6[0];
    Gf[l * 6 + 1] = o6[1];
    Gf[l * 6 + 2] = o6[2];
    Gf[l * 6 + 3] = o6[3];
    Gf[l * 6 + 4] = o6[4];
    Gf[l * 6 + 5] = o6[5];
    asm volatile("s_waitcnt lgkmcnt(0)" ::: "memory");

    odst_j[l] = GW[l];
    if (l < 32) odst_j[64 + l] = GW[64 + l];
}

// ---- prologue: nodes [N,7] -> d_ws [N,8] (32B records, 16B-aligned) ----
__global__ void __launch_bounds__(BLOCK) repack_nodes_kernel(
    const float* __restrict__ nodes, float* __restrict__ nodes8, int total7)
{
    int idx = blockIdx.x * BLOCK + threadIdx.x;
    int stride = gridDim.x * BLOCK;
    for (; idx < total7; idx += stride) {
        int node = idx / 7;
        int comp = idx - node * 7;
        nodes8[node * 8 + comp] = nodes[idx];
    }
}

__global__ void __launch_bounds__(BLOCK) pose_graph_kernel(
    const int* __restrict__ edges,     // [n,2] int32
    const float* __restrict__ poses,   // [n,7]
    const float* __restrict__ nodes8,  // [N_NODES,8] repacked
    float* __restrict__ out,           // [n,6]
    int n)
{
    __shared__ float4 G[4][2][256];   // 32 KiB: per-wave double-buffered landing zones

    const int tid = threadIdx.x;
    const int l = tid & 63;
    const int w = tid >> 6;
    const long long base = (long long)blockIdx.x * TILE;

    if (base + TILE <= (long long)n) {
        const long long e0 = base + tid;

        // edge indices for all 4 iterations (coalesced int2)
        const int2 ed0 = ((const int2*)edges)[e0];
        const int2 ed1 = ((const int2*)edges)[e0 + BLOCK];
        const int2 ed2 = ((const int2*)edges)[e0 + 2 * BLOCK];
        const int2 ed3 = ((const int2*)edges)[e0 + 3 * BLOCK];

        float4* odst = (float4*)(out + base * 6);   // 16B-aligned (base*24B)
        float4* B0 = &G[w][0][0];
        float4* B1 = &G[w][1][0];

        float pa0[4], pb0[4], pa1[4], pb1[4];       // pose ping-pong reg sets

        // ---- prologue: prefetch iteration 0 ----
        gather_wave(nodes8, ed0, l, B0);
        load_pose(poses, e0, pa0, pb0);

        // ---- j=0: prefetch j=1, wait j=0's gathers only, compute ----
        gather_wave(nodes8, ed1, l, B1);
        load_pose(poses, e0 + BLOCK, pa1, pb1);
        asm volatile("s_waitcnt vmcnt(8)" ::: "memory");   // drains G0 (+P0 via compiler)
        __builtin_amdgcn_sched_barrier(0);
        compute_store(pa0, pb0, B0, odst + 0 * 384 + w * 96, l);

        // ---- j=1 ----
        gather_wave(nodes8, ed2, l, B0);
        load_pose(poses, e0 + 2 * BLOCK, pa0, pb0);
        asm volatile("s_waitcnt vmcnt(8)" ::: "memory");   // drains G1
        __builtin_amdgcn_sched_barrier(0);
        compute_store(pa1, pb1, B1, odst + 1 * 384 + w * 96, l);

        // ---- j=2 ----
        gather_wave(nodes8, ed3, l, B1);
        load_pose(poses, e0 + 3 * BLOCK, pa1, pb1);
        asm volatile("s_waitcnt vmcnt(8)" ::: "memory");   // drains G2
        __builtin_amdgcn_sched_barrier(0);
        compute_store(pa0, pb0, B0, odst + 2 * 384 + w * 96, l);

        // ---- j=3 (no prefetch) ----
        asm volatile("s_waitcnt vmcnt(0)" ::: "memory");   // drains G3 + P3
        __builtin_amdgcn_sched_barrier(0);
        compute_store(pa1, pb1, B1, odst + 3 * 384 + w * 96, l);
    } else {
        // ---- tail tile (absent at n=3.2M): per-edge scalar path ----
        for (int j = 0; j < CPT; ++j) {
            const long long e = base + j * BLOCK + tid;
            if (e < (long long)n) {
                const int2 ed = ((const int2*)edges)[e];
                float pa[4], pb[4];
                load_pose(poses, e, pa, pb);
                const float4* n1p = (const float4*)(nodes8 + (size_t)ed.x * 8);
                const float4* n2p = (const float4*)(nodes8 + (size_t)ed.y * 8);
                float4 a1 = n1p[0], b1 = n1p[1];
                float4 a2 = n2p[0], b2 = n2p[1];
                F3 tp{pa[0], pa[1], pa[2]};
                F4 qp{pb[0], pb[1], pb[2], pb[3]};
                F3 t1{a1.x, a1.y, a1.z};
                F4 q1{a1.w, b1.x, b1.y, b1.z};
                F3 t2{a2.x, a2.y, a2.z};
                F4 q2{a2.w, b2.x, b2.y, b2.z};
                float o6[6];
                se3_error_log(tp, qp, t1, q1, t2, q2, o6);
                float* op = out + e * 6;
                op[0] = o6[0]; op[1] = o6[1]; op[2] = o6[2];
                op[3] = o6[3]; op[4] = o6[4]; op[5] = o6[5];
            }
        }
    }
}

// fallback (ws too small): direct scalar gathers from [N,7] nodes
__global__ void __launch_bounds__(BLOCK) pose_graph_kernel_fallback(
    const int* __restrict__ edges, const float* __restrict__ poses,
    const float* __restrict__ nodes, float* __restrict__ out, int n)
{
    const int tid = threadIdx.x;
    const long long base = (long long)blockIdx.x * BLOCK;
    const int limit = (int)min((long long)BLOCK, (long long)n - base);
    if (tid < limit) {
        const long long e = base + tid;
        const int2 ed = ((const int2*)edges)[e];
        const float* pp = poses + e * 7;
        F3 tp{pp[0], pp[1], pp[2]};
        F4 qp{pp[3], pp[4], pp[5], pp[6]};
        const float* n1p = nodes + (size_t)ed.x * 7;
        const float* n2p = nodes + (size_t)ed.y * 7;
        F3 t1{n1p[0], n1p[1], n1p[2]};
        F4 q1{n1p[3], n1p[4], n1p[5], n1p[6]};
        F3 t2{n2p[0], n2p[1], n2p[2]};
        F4 q2{n2p[3], n2p[4], n2p[5], n2p[6]};
        float o6[6];
        se3_error_log(tp, qp, t1, q1, t2, q2, o6);
        float* op = out + e * 6;
        op[0] = o6[0]; op[1] = o6[1]; op[2] = o6[2];
        op[3] = o6[3]; op[4] = o6[4]; op[5] = o6[5];
    }
}

extern "C" void kernel_launch(void* const* d_in, const int* in_sizes, int n_in,
                              void* d_out, int out_size, void* d_ws, size_t ws_size,
                              hipStream_t stream) {
    const int* edges = (const int*)d_in[0];
    const float* poses = (const float*)d_in[1];
    const float* nodes = (const float*)d_in[2];
    float* out = (float*)d_out;

    const int n_edges = in_sizes[0] / 2;
    const int n_nodes = in_sizes[2] / 7;

    const size_t ws_needed = (size_t)n_nodes * 8 * sizeof(float);
    if (ws_size >= ws_needed) {
        float* nodes8 = (float*)d_ws;
        const int total7 = n_nodes * 7;
        const int rgrid = (total7 + BLOCK - 1) / BLOCK;
        const int grid = (n_edges + TILE - 1) / TILE;
        repack_nodes_kernel<<<rgrid, BLOCK, 0, stream>>>(nodes, nodes8, total7);
        pose_graph_kernel<<<grid, BLOCK, 0, stream>>>(edges, poses, nodes8, out, n_edges);
    } else {
        const int grid = (n_edges + BLOCK - 1) / BLOCK;
        pose_graph_kernel_fallback<<<grid, BLOCK, 0, stream>>>(edges, poses, nodes, out, n_edges);
    }
}